// Round 1
// baseline (949.542 us; speedup 1.0000x reference)
//
#include <hip/hip_runtime.h>

#define RL(x) __builtin_amdgcn_readfirstlane(x)

// ---------------- conv1: x[1024,4,84,84] -> c1[1024,32,20,20], k=8, s=4 ----------------
// out = relu(conv(x)/256 + b). One block per image; 4 waves = 4 oc-groups of 8;
// 64 lanes cover 400 pixels in 7 slots. Weights via wave-uniform s_loads.
__global__ __launch_bounds__(256) void conv1_k(const float* __restrict__ x,
                                               const float* __restrict__ w,    // [32,4,8,8]
                                               const float* __restrict__ bias,
                                               float* __restrict__ out) {
  const int b    = blockIdx.x;
  const int tid  = threadIdx.x;
  const int lane = tid & 63;
  const int oc0  = RL(tid >> 6) * 8;   // wave-uniform oc group

  int pstore[7], pvalid[7], ibase[7];
#pragma unroll
  for (int s = 0; s < 7; ++s) {
    int p = lane + 64 * s;
    pstore[s] = p;
    pvalid[s] = (p < 400);
    if (p > 399) p = 399;
    int py = p / 20, px = p - (p / 20) * 20;
    ibase[s] = (4 * py) * 84 + 4 * px;   // 16B-aligned (84*4B=336B, 16px B)
  }

  float acc[7][8];
#pragma unroll
  for (int s = 0; s < 7; ++s)
#pragma unroll
    for (int j = 0; j < 8; ++j) acc[s][j] = 0.f;

  const float* xb = x + b * (4 * 84 * 84);
#pragma unroll 1
  for (int ic = 0; ic < 4; ++ic) {
    const float* xc = xb + ic * (84 * 84);
    const float* wc = w + oc0 * 256 + ic * 64;  // w flat: oc*256 + ic*64 + ky*8 + kx
#pragma unroll 1
    for (int ky = 0; ky < 8; ++ky) {
      float in8[7][8];
#pragma unroll
      for (int s = 0; s < 7; ++s) {
        const float* ip = xc + ky * 84 + ibase[s];
        float4 a = *(const float4*)ip;
        float4 c = *(const float4*)(ip + 4);
        in8[s][0]=a.x; in8[s][1]=a.y; in8[s][2]=a.z; in8[s][3]=a.w;
        in8[s][4]=c.x; in8[s][5]=c.y; in8[s][6]=c.z; in8[s][7]=c.w;
      }
#pragma unroll
      for (int j = 0; j < 8; ++j) {
        const float* wp = wc + j * 256 + ky * 8;  // uniform -> s_load
        float wv[8];
#pragma unroll
        for (int kx = 0; kx < 8; ++kx) wv[kx] = wp[kx];
#pragma unroll
        for (int s = 0; s < 7; ++s)
#pragma unroll
          for (int kx = 0; kx < 8; ++kx)
            acc[s][j] = fmaf(in8[s][kx], wv[kx], acc[s][j]);
      }
    }
  }
  const float inv256 = 1.0f / 256.0f;
#pragma unroll
  for (int j = 0; j < 8; ++j) {
    float bj = bias[oc0 + j];
    float* op = out + (b * 32 + oc0 + j) * 400;
#pragma unroll
    for (int s = 0; s < 7; ++s) {
      if (pvalid[s]) {
        float v = acc[s][j] * inv256 + bj;
        op[pstore[s]] = v > 0.f ? v : 0.f;
      }
    }
  }
}

// ---------------- conv2: c1[1024,32,20,20] -> c2[1024,64,9,9], k=4, s=2 ----------------
// 2 images per block (162 px over 3 lane-slots); 4 waves = 4 oc-groups of 16.
__global__ __launch_bounds__(256) void conv2_k(const float* __restrict__ in,
                                               const float* __restrict__ w,   // [64,32,4,4]
                                               const float* __restrict__ bias,
                                               float* __restrict__ out) {
  const int b0   = blockIdx.x * 2;
  const int tid  = threadIdx.x;
  const int lane = tid & 63;
  const int oc0  = RL(tid >> 6) * 16;

  int valid[3], sb[3], sp[3], ib[3];
#pragma unroll
  for (int s = 0; s < 3; ++s) {
    int q = lane + 64 * s;
    valid[s] = (q < 162);
    if (q > 161) q = 161;
    int bb = q / 81;
    int p  = q - bb * 81;
    int py = p / 9, px = p - py * 9;
    sb[s] = b0 + bb;
    sp[s] = p;
    ib[s] = (b0 + bb) * 12800 + (2 * py) * 20 + 2 * px;
  }

  float acc[3][16];
#pragma unroll
  for (int s = 0; s < 3; ++s)
#pragma unroll
    for (int j = 0; j < 16; ++j) acc[s][j] = 0.f;

#pragma unroll 1
  for (int ic = 0; ic < 32; ++ic) {
#pragma unroll
    for (int ky = 0; ky < 4; ++ky) {
      float in4[3][4];
#pragma unroll
      for (int s = 0; s < 3; ++s) {
        const float* ip = in + ib[s] + ic * 400 + ky * 20;
        float2 a = *(const float2*)ip;        // 8B-aligned (2px*4B)
        float2 c = *(const float2*)(ip + 2);
        in4[s][0]=a.x; in4[s][1]=a.y; in4[s][2]=c.x; in4[s][3]=c.y;
      }
#pragma unroll
      for (int j = 0; j < 16; ++j) {
        const float* wp = w + ((oc0 + j) * 32 + ic) * 16 + ky * 4;  // uniform
        float wv[4];
#pragma unroll
        for (int kx = 0; kx < 4; ++kx) wv[kx] = wp[kx];
#pragma unroll
        for (int s = 0; s < 3; ++s)
#pragma unroll
          for (int kx = 0; kx < 4; ++kx)
            acc[s][j] = fmaf(in4[s][kx], wv[kx], acc[s][j]);
      }
    }
  }
#pragma unroll
  for (int j = 0; j < 16; ++j) {
    float bj = bias[oc0 + j];
#pragma unroll
    for (int s = 0; s < 3; ++s) {
      if (valid[s]) {
        float v = acc[s][j] + bj;
        out[(sb[s] * 64 + oc0 + j) * 81 + sp[s]] = v > 0.f ? v : 0.f;
      }
    }
  }
}

// ---------------- conv3: c2[1024,64,9,9] -> c3[1024,64,7,7], k=3, s=1 ----------------
// 4 images per block (196 px over 4 lane-slots); 4 waves = 4 oc-groups of 16.
__global__ __launch_bounds__(256) void conv3_k(const float* __restrict__ in,
                                               const float* __restrict__ w,   // [64,64,3,3]
                                               const float* __restrict__ bias,
                                               float* __restrict__ out) {
  const int b0   = blockIdx.x * 4;
  const int tid  = threadIdx.x;
  const int lane = tid & 63;
  const int oc0  = RL(tid >> 6) * 16;

  int valid[4], sb[4], sp[4], ib[4];
#pragma unroll
  for (int s = 0; s < 4; ++s) {
    int q = lane + 64 * s;
    valid[s] = (q < 196);
    if (q > 195) q = 195;
    int bb = q / 49;
    int p  = q - bb * 49;
    int py = p / 7, px = p - py * 7;
    sb[s] = b0 + bb;
    sp[s] = p;
    ib[s] = (b0 + bb) * 5184 + py * 9 + px;
  }

  float acc[4][16];
#pragma unroll
  for (int s = 0; s < 4; ++s)
#pragma unroll
    for (int j = 0; j < 16; ++j) acc[s][j] = 0.f;

#pragma unroll 1
  for (int ic = 0; ic < 64; ++ic) {
#pragma unroll
    for (int ky = 0; ky < 3; ++ky) {
      float in3[4][3];
#pragma unroll
      for (int s = 0; s < 4; ++s) {
        const float* ip = in + ib[s] + ic * 81 + ky * 9;
        in3[s][0] = ip[0]; in3[s][1] = ip[1]; in3[s][2] = ip[2];
      }
#pragma unroll
      for (int j = 0; j < 16; ++j) {
        const float* wp = w + ((oc0 + j) * 64 + ic) * 9 + ky * 3;  // uniform
        float wv[3];
        wv[0] = wp[0]; wv[1] = wp[1]; wv[2] = wp[2];
#pragma unroll
        for (int s = 0; s < 4; ++s)
#pragma unroll
          for (int kx = 0; kx < 3; ++kx)
            acc[s][j] = fmaf(in3[s][kx], wv[kx], acc[s][j]);
      }
    }
  }
#pragma unroll
  for (int j = 0; j < 16; ++j) {
    float bj = bias[oc0 + j];
#pragma unroll
    for (int s = 0; s < 4; ++s) {
      if (valid[s]) {
        float v = acc[s][j] + bj;
        out[sb[s] * 3136 + (oc0 + j) * 49 + sp[s]] = v > 0.f ? v : 0.f;
      }
    }
  }
}

// ---------------- fc1a: c3[1024][3136] @ fw1[3136][256] -> partial[8][1024][256] ----------------
// Grid (32 b-blocks, 8 k-chunks). Block: 32 imgs x 256 j; thread microtile 8 imgs x 4 j.
// A-tile staged transposed in LDS; reads are wave-broadcast (conflict-free).
__global__ __launch_bounds__(256) void fc1a_k(const float* __restrict__ a,
                                              const float* __restrict__ w,
                                              float* __restrict__ part) {
  __shared__ float al[56][36];   // row = 144B (16B-aligned)
  const int b0  = blockIdx.x * 32;
  const int k0  = blockIdx.y * 392;
  const int tid = threadIdx.x;
  const int jj  = tid & 63;
  const int ib  = RL(tid >> 6);  // 0..3 -> imgs ib*8..ib*8+7

  float acc[8][4];
#pragma unroll
  for (int r = 0; r < 8; ++r)
#pragma unroll
    for (int c = 0; c < 4; ++c) acc[r][c] = 0.f;

#pragma unroll 1
  for (int t = 0; t < 7; ++t) {
    __syncthreads();
    for (int idx = tid; idx < 1792; idx += 256) {
      int i = idx / 56, kk = idx - i * 56;
      al[kk][i] = a[(b0 + i) * 3136 + k0 + t * 56 + kk];
    }
    __syncthreads();
#pragma unroll 1
    for (int kk = 0; kk < 56; ++kk) {
      float4 wv = *(const float4*)&w[(k0 + t * 56 + kk) * 256 + jj * 4];
      const float4* ap = (const float4*)&al[kk][ib * 8];
      float4 a0 = ap[0], a1 = ap[1];
      float av[8] = {a0.x, a0.y, a0.z, a0.w, a1.x, a1.y, a1.z, a1.w};
#pragma unroll
      for (int r = 0; r < 8; ++r) {
        acc[r][0] = fmaf(av[r], wv.x, acc[r][0]);
        acc[r][1] = fmaf(av[r], wv.y, acc[r][1]);
        acc[r][2] = fmaf(av[r], wv.z, acc[r][2]);
        acc[r][3] = fmaf(av[r], wv.w, acc[r][3]);
      }
    }
  }
#pragma unroll
  for (int r = 0; r < 8; ++r) {
    float4 v = {acc[r][0], acc[r][1], acc[r][2], acc[r][3]};
    *(float4*)&part[(blockIdx.y * 1024 + b0 + ib * 8 + r) * 256 + jj * 4] = v;
  }
}

// ---------------- fc1b: reduce 8 partials + bias + relu -> h[1024][256] ----------------
__global__ __launch_bounds__(256) void fc1b_k(const float* __restrict__ part,
                                              const float* __restrict__ bias,
                                              float* __restrict__ h) {
  int idx = blockIdx.x * 256 + threadIdx.x;
  int j = idx & 255;
  float s = bias[j];
#pragma unroll
  for (int c = 0; c < 8; ++c) s += part[c * 262144 + idx];
  h[idx] = s > 0.f ? s : 0.f;
}

// ---------------- fc2 + softmax + dist/res ----------------
// 4 images per block (one wave each). Lane j computes logit j (j<51), wave-shuffle softmax.
__global__ __launch_bounds__(256) void fc2_k(const float* __restrict__ h,
                                             const float* __restrict__ w,   // [256][51]
                                             const float* __restrict__ bias,
                                             const float* __restrict__ z,
                                             float* __restrict__ dist,      // [1024][6][51]
                                             float* __restrict__ res) {     // [1024][6]
  const int tid = threadIdx.x;
  const int j   = tid & 63;
  const int b   = blockIdx.x * 4 + RL(tid >> 6);
  const float* hb = h + b * 256;
  const int jc = j < 51 ? j : 50;
  float acc = bias[jc];
#pragma unroll 4
  for (int k = 0; k < 256; ++k)
    acc = fmaf(hb[k], w[k * 51 + jc], acc);   // hb[k] uniform -> s_load
  float logit = (j < 51) ? acc : -1e30f;
  float m = logit;
#pragma unroll
  for (int o = 32; o > 0; o >>= 1) m = fmaxf(m, __shfl_xor(m, o, 64));
  float e = (j < 51) ? __expf(logit - m) : 0.f;
  float ssum = e;
#pragma unroll
  for (int o = 32; o > 0; o >>= 1) ssum += __shfl_xor(ssum, o, 64);
  float p = e / ssum;
  float zv = (j < 51) ? z[jc] : 0.f;
  float rz = p * zv;
#pragma unroll
  for (int o = 32; o > 0; o >>= 1) rz += __shfl_xor(rz, o, 64);
  if (j < 51) {
    float* db = dist + b * 6 * 51 + j;
#pragma unroll
    for (int n = 0; n < 6; ++n) db[n * 51] = p;
  }
  if (j < 6) res[b * 6 + j] = rz;
}

extern "C" void kernel_launch(void* const* d_in, const int* in_sizes, int n_in,
                              void* d_out, int out_size, void* d_ws, size_t ws_size,
                              hipStream_t stream) {
  const float* x   = (const float*)d_in[0];
  const float* cw1 = (const float*)d_in[1];
  const float* cb1 = (const float*)d_in[2];
  const float* cw2 = (const float*)d_in[3];
  const float* cb2 = (const float*)d_in[4];
  const float* cw3 = (const float*)d_in[5];
  const float* cb3 = (const float*)d_in[6];
  const float* fw1 = (const float*)d_in[7];
  const float* fb1 = (const float*)d_in[8];
  const float* fw2 = (const float*)d_in[9];
  const float* fb2 = (const float*)d_in[10];
  const float* z   = (const float*)d_in[11];
  // n_out (d_in[12]) is the constant 6; shapes are baked into out_size.

  float* ws = (float*)d_ws;
  // c1: [0, 13107200)            1024*32*400 floats
  // c2: [13107200, 18415616)     1024*64*81
  // c3: [0, 3211264)             reuses dead c1
  // pw: [13107200, 15204352)     8*1024*256, reuses dead c2
  // h : [15204352, 15466496)
  float* c1 = ws;
  float* c2 = ws + 13107200;
  float* c3 = ws;
  float* pw = ws + 13107200;
  float* h  = ws + 15204352;

  float* dist = (float*)d_out;
  float* res  = dist + 1024 * 6 * 51;

  conv1_k<<<1024, 256, 0, stream>>>(x, cw1, cb1, c1);
  conv2_k<<<512, 256, 0, stream>>>(c1, cw2, cb2, c2);
  conv3_k<<<256, 256, 0, stream>>>(c2, cw3, cb3, c3);
  fc1a_k<<<dim3(32, 8), 256, 0, stream>>>(c3, fw1, pw);
  fc1b_k<<<1024, 256, 0, stream>>>(pw, fb1, h);
  fc2_k<<<256, 256, 0, stream>>>(h, fw2, fb2, z, dist, res);
}

// Round 2
// 900.427 us; speedup vs baseline: 1.0545x; 1.0545x over previous
//
#include <hip/hip_runtime.h>

#define RL(x) __builtin_amdgcn_readfirstlane(x)

// ---------------- conv1: x[1024,4,84,84] -> c1[1024,32,20,20], k=8, s=4 ----------------
// lanes = 32 oc x 2 row-halves. Block = 5 waves = 1 image; wave w, half h owns
// output rows {2u, 2u+1}, u = 2w+h (u=0..9 covers all 20 rows). Weights are
// lane-distributed (resident per (ic,ky)); input rows are uniform-per-half
// float4 loads.
__global__ __launch_bounds__(320) void conv1_k(const float* __restrict__ x,
                                               const float* __restrict__ w,    // [32,4,8,8]
                                               const float* __restrict__ bias,
                                               float* __restrict__ out) {
  const int b    = blockIdx.x;
  const int tid  = threadIdx.x;
  const int lane = tid & 63;
  const int j    = lane & 31;          // oc
  const int h    = lane >> 5;          // row-half
  const int wv   = RL(tid >> 6);       // 0..4
  const int u    = 2 * wv + h;         // 0..9

  float acc[2][20];
#pragma unroll
  for (int rr = 0; rr < 2; ++rr)
#pragma unroll
    for (int px = 0; px < 20; ++px) acc[rr][px] = 0.f;

  const float* xb = x + b * 28224;
  const float* wj = w + j * 256;

#pragma unroll 1
  for (int ic = 0; ic < 4; ++ic) {
    const float* xc = xb + ic * 7056;
    const float* wb = wj + ic * 64;
#pragma unroll 1
    for (int ky = 0; ky < 8; ++ky) {
      float4 w0 = *(const float4*)(wb + ky * 8);
      float4 w1 = *(const float4*)(wb + ky * 8 + 4);
      float wk[8] = {w0.x, w0.y, w0.z, w0.w, w1.x, w1.y, w1.z, w1.w};
#pragma unroll
      for (int rr = 0; rr < 2; ++rr) {
        const float* rp = xc + (8 * u + 4 * rr + ky) * 84;  // row 0..83
        // chunk A: cols 0..47 -> px 0..9
        float fA[48];
#pragma unroll
        for (int q = 0; q < 12; ++q) {
          float4 t = *(const float4*)(rp + q * 4);
          fA[q * 4] = t.x; fA[q * 4 + 1] = t.y; fA[q * 4 + 2] = t.z; fA[q * 4 + 3] = t.w;
        }
#pragma unroll
        for (int px = 0; px < 10; ++px)
#pragma unroll
          for (int kx = 0; kx < 8; ++kx)
            acc[rr][px] = fmaf(fA[4 * px + kx], wk[kx], acc[rr][px]);
        // chunk B: cols 40..83 -> px 10..19
        float fB[44];
#pragma unroll
        for (int q = 0; q < 11; ++q) {
          float4 t = *(const float4*)(rp + 40 + q * 4);
          fB[q * 4] = t.x; fB[q * 4 + 1] = t.y; fB[q * 4 + 2] = t.z; fB[q * 4 + 3] = t.w;
        }
#pragma unroll
        for (int px = 10; px < 20; ++px)
#pragma unroll
          for (int kx = 0; kx < 8; ++kx)
            acc[rr][px] = fmaf(fB[4 * px + kx - 40], wk[kx], acc[rr][px]);
      }
    }
  }

  const float inv256 = 1.0f / 256.0f;
  const float bj = bias[j];
#pragma unroll
  for (int rr = 0; rr < 2; ++rr) {
    float* op = out + ((b * 32 + j) * 20 + (2 * u + rr)) * 20;
#pragma unroll
    for (int q = 0; q < 5; ++q) {
      float4 v;
      float v0 = acc[rr][q * 4 + 0] * inv256 + bj;
      float v1 = acc[rr][q * 4 + 1] * inv256 + bj;
      float v2 = acc[rr][q * 4 + 2] * inv256 + bj;
      float v3 = acc[rr][q * 4 + 3] * inv256 + bj;
      v.x = v0 > 0.f ? v0 : 0.f; v.y = v1 > 0.f ? v1 : 0.f;
      v.z = v2 > 0.f ? v2 : 0.f; v.w = v3 > 0.f ? v3 : 0.f;
      *(float4*)(op + q * 4) = v;
    }
  }
}

// ---------------- conv2: c1[1024,32,20,20] -> c2[1024,64,9,9], k=4, s=2 ----------------
// lanes = 64 oc. Block = 5 waves = 1 image; wave w owns output rows {2w,2w+1}
// (wave 4: row 8 only). Weights lane-distributed; input rows uniform float4.
__global__ __launch_bounds__(320) void conv2_k(const float* __restrict__ in,
                                               const float* __restrict__ w,   // [64,32,4,4]
                                               const float* __restrict__ bias,
                                               float* __restrict__ out) {
  const int b   = blockIdx.x;
  const int tid = threadIdx.x;
  const int j   = tid & 63;            // oc
  const int wv  = RL(tid >> 6);        // 0..4
  const int py0 = 2 * wv;
  const int nr  = (wv == 4) ? 1 : 2;

  float acc[2][9];
#pragma unroll
  for (int rr = 0; rr < 2; ++rr)
#pragma unroll
    for (int px = 0; px < 9; ++px) acc[rr][px] = 0.f;

  const float* inb = in + b * 12800;
  const float* wj  = w + j * 512;

#pragma unroll 1
  for (int ic = 0; ic < 32; ++ic) {
    const float* icp = inb + ic * 400;
    const float* wp  = wj + ic * 16;
#pragma unroll 1
    for (int ky = 0; ky < 4; ++ky) {
      float4 wk4 = *(const float4*)(wp + ky * 4);
      float wk[4] = {wk4.x, wk4.y, wk4.z, wk4.w};
      const float* r0p = icp + (4 * wv + ky) * 20;   // input row 2*py0+ky
      float rA[20];
#pragma unroll
      for (int q = 0; q < 5; ++q) {
        float4 t = *(const float4*)(r0p + q * 4);
        rA[q * 4] = t.x; rA[q * 4 + 1] = t.y; rA[q * 4 + 2] = t.z; rA[q * 4 + 3] = t.w;
      }
#pragma unroll
      for (int px = 0; px < 9; ++px)
#pragma unroll
        for (int kx = 0; kx < 4; ++kx)
          acc[0][px] = fmaf(rA[2 * px + kx], wk[kx], acc[0][px]);
      if (nr == 2) {
        float rB[20];
#pragma unroll
        for (int q = 0; q < 5; ++q) {
          float4 t = *(const float4*)(r0p + 40 + q * 4);  // row +2
          rB[q * 4] = t.x; rB[q * 4 + 1] = t.y; rB[q * 4 + 2] = t.z; rB[q * 4 + 3] = t.w;
        }
#pragma unroll
        for (int px = 0; px < 9; ++px)
#pragma unroll
          for (int kx = 0; kx < 4; ++kx)
            acc[1][px] = fmaf(rB[2 * px + kx], wk[kx], acc[1][px]);
      }
    }
  }

  const float bj = bias[j];
#pragma unroll
  for (int rr = 0; rr < 2; ++rr) {
    if (rr < nr) {
      float* op = out + (b * 64 + j) * 81 + (py0 + rr) * 9;
#pragma unroll
      for (int px = 0; px < 9; ++px) {
        float v = acc[rr][px] + bj;
        op[px] = v > 0.f ? v : 0.f;
      }
    }
  }
}

// ---------------- conv3: c2[1024,64,9,9] -> c3[1024,64,7,7], k=3, s=1 ----------------
// lanes = 64 oc. Block = 4 waves = 1 image; wave (rotated by b for SIMD load
// balance) owns rows {2w,2w+1} (wave 3: row 6). Rows r,r+1 are 18 contiguous
// floats; parity (ic+ky)&1 made static by splitting ic into even/odd pairs.
__global__ __launch_bounds__(256) void conv3_k(const float* __restrict__ in,
                                               const float* __restrict__ w,   // [64,64,3,3]
                                               const float* __restrict__ bias,
                                               float* __restrict__ out) {
  const int b   = blockIdx.x;
  const int tid = threadIdx.x;
  const int j   = tid & 63;
  const int wv  = (RL(tid >> 6) + b) & 3;
  const int py0 = 2 * wv;
  const int nr  = (wv == 3) ? 1 : 2;

  float acc[2][7];
#pragma unroll
  for (int rr = 0; rr < 2; ++rr)
#pragma unroll
    for (int px = 0; px < 7; ++px) acc[rr][px] = 0.f;

  const float* inb = in + b * 5184;
  const float* wj  = w + j * 576;

#pragma unroll 1
  for (int ic2 = 0; ic2 < 32; ++ic2) {
#pragma unroll
    for (int e = 0; e < 2; ++e) {
      const int ic = 2 * ic2 + e;
      const float* icp = inb + ic * 81;
      const float* wp  = wj + ic * 9;
      float w9[9];
#pragma unroll
      for (int t = 0; t < 9; ++t) w9[t] = wp[t];
#pragma unroll
      for (int ky = 0; ky < 3; ++ky) {
        const int r = py0 + ky;
        const float* bp = icp + r * 9;
        // parity of (ic*81 + r*9) = (e + ky) & 1  (py0 even) — static here
        float in18[18];
        if (nr == 2) {
          if (((e + ky) & 1) == 0) {
#pragma unroll
            for (int q = 0; q < 9; ++q) {
              float2 t = *(const float2*)(bp + 2 * q);
              in18[2 * q] = t.x; in18[2 * q + 1] = t.y;
            }
          } else {
            in18[0] = bp[0];
#pragma unroll
            for (int q = 0; q < 8; ++q) {
              float2 t = *(const float2*)(bp + 1 + 2 * q);
              in18[1 + 2 * q] = t.x; in18[2 + 2 * q] = t.y;
            }
            in18[17] = bp[17];
          }
        } else {
          if (((e + ky) & 1) == 0) {
#pragma unroll
            for (int q = 0; q < 4; ++q) {
              float2 t = *(const float2*)(bp + 2 * q);
              in18[2 * q] = t.x; in18[2 * q + 1] = t.y;
            }
            in18[8] = bp[8];
          } else {
            in18[0] = bp[0];
#pragma unroll
            for (int q = 0; q < 4; ++q) {
              float2 t = *(const float2*)(bp + 1 + 2 * q);
              in18[1 + 2 * q] = t.x; in18[2 + 2 * q] = t.y;
            }
          }
#pragma unroll
          for (int q = 9; q < 18; ++q) in18[q] = 0.f;
        }
#pragma unroll
        for (int rr = 0; rr < 2; ++rr) {
          if (rr < nr) {
#pragma unroll
            for (int px = 0; px < 7; ++px)
#pragma unroll
              for (int kx = 0; kx < 3; ++kx)
                acc[rr][px] = fmaf(in18[rr * 9 + px + kx], w9[ky * 3 + kx], acc[rr][px]);
          }
        }
      }
    }
  }

  const float bj = bias[j];
#pragma unroll
  for (int rr = 0; rr < 2; ++rr) {
    if (rr < nr) {
      float* op = out + b * 3136 + j * 49 + (py0 + rr) * 7;
#pragma unroll
      for (int px = 0; px < 7; ++px) {
        float v = acc[rr][px] + bj;
        op[px] = v > 0.f ? v : 0.f;
      }
    }
  }
}

// ---------------- fc1a: c3[1024][3136] @ fw1[3136][256] -> partial[8][1024][256] ----------------
// Grid (64 b-blocks of 16 imgs, 8 k-chunks of 392). Thread microtile 4 imgs x 4 j.
// A-tile transposed in LDS; reads wave-broadcast (conflict-free).
__global__ __launch_bounds__(256) void fc1a_k(const float* __restrict__ a,
                                              const float* __restrict__ w,
                                              float* __restrict__ part) {
  __shared__ float al[56][20];   // row = 80 B (16B-aligned)
  const int b0  = blockIdx.x * 16;
  const int k0  = blockIdx.y * 392;
  const int tid = threadIdx.x;
  const int jj  = tid & 63;
  const int ib  = RL(tid >> 6);  // imgs ib*4 .. ib*4+3

  float acc[4][4];
#pragma unroll
  for (int r = 0; r < 4; ++r)
#pragma unroll
    for (int c = 0; c < 4; ++c) acc[r][c] = 0.f;

#pragma unroll 1
  for (int t = 0; t < 7; ++t) {
    __syncthreads();
#pragma unroll
    for (int z = 0; z < 4; ++z) {
      int idx = tid + z * 256;
      if (idx < 896) {
        int i = idx / 56, kk = idx - i * 56;
        al[kk][i] = a[(b0 + i) * 3136 + k0 + t * 56 + kk];
      }
    }
    __syncthreads();
#pragma unroll 2
    for (int kk = 0; kk < 56; ++kk) {
      float4 wv4 = *(const float4*)&w[(k0 + t * 56 + kk) * 256 + jj * 4];
      float4 av  = *(const float4*)&al[kk][ib * 4];
      float avr[4] = {av.x, av.y, av.z, av.w};
#pragma unroll
      for (int r = 0; r < 4; ++r) {
        acc[r][0] = fmaf(avr[r], wv4.x, acc[r][0]);
        acc[r][1] = fmaf(avr[r], wv4.y, acc[r][1]);
        acc[r][2] = fmaf(avr[r], wv4.z, acc[r][2]);
        acc[r][3] = fmaf(avr[r], wv4.w, acc[r][3]);
      }
    }
  }
#pragma unroll
  for (int r = 0; r < 4; ++r) {
    float4 v = {acc[r][0], acc[r][1], acc[r][2], acc[r][3]};
    *(float4*)&part[(blockIdx.y * 1024 + b0 + ib * 4 + r) * 256 + jj * 4] = v;
  }
}

// ---------------- fc1b: reduce 8 partials + bias + relu -> h[1024][256] ----------------
__global__ __launch_bounds__(256) void fc1b_k(const float* __restrict__ part,
                                              const float* __restrict__ bias,
                                              float* __restrict__ h) {
  int idx = blockIdx.x * 256 + threadIdx.x;
  int j = idx & 255;
  float s = bias[j];
#pragma unroll
  for (int c = 0; c < 8; ++c) s += part[c * 262144 + idx];
  h[idx] = s > 0.f ? s : 0.f;
}

// ---------------- fc2 + softmax + dist/res ----------------
__global__ __launch_bounds__(256) void fc2_k(const float* __restrict__ h,
                                             const float* __restrict__ w,   // [256][51]
                                             const float* __restrict__ bias,
                                             const float* __restrict__ z,
                                             float* __restrict__ dist,      // [1024][6][51]
                                             float* __restrict__ res) {     // [1024][6]
  const int tid = threadIdx.x;
  const int j   = tid & 63;
  const int b   = blockIdx.x * 4 + RL(tid >> 6);
  const float* hb = h + b * 256;
  const int jc = j < 51 ? j : 50;
  float acc = bias[jc];
#pragma unroll 4
  for (int k = 0; k < 256; ++k)
    acc = fmaf(hb[k], w[k * 51 + jc], acc);
  float logit = (j < 51) ? acc : -1e30f;
  float m = logit;
#pragma unroll
  for (int o = 32; o > 0; o >>= 1) m = fmaxf(m, __shfl_xor(m, o, 64));
  float e = (j < 51) ? __expf(logit - m) : 0.f;
  float ssum = e;
#pragma unroll
  for (int o = 32; o > 0; o >>= 1) ssum += __shfl_xor(ssum, o, 64);
  float p = e / ssum;
  float zv = (j < 51) ? z[jc] : 0.f;
  float rz = p * zv;
#pragma unroll
  for (int o = 32; o > 0; o >>= 1) rz += __shfl_xor(rz, o, 64);
  if (j < 51) {
    float* db = dist + b * 6 * 51 + j;
#pragma unroll
    for (int n = 0; n < 6; ++n) db[n * 51] = p;
  }
  if (j < 6) res[b * 6 + j] = rz;
}

extern "C" void kernel_launch(void* const* d_in, const int* in_sizes, int n_in,
                              void* d_out, int out_size, void* d_ws, size_t ws_size,
                              hipStream_t stream) {
  const float* x   = (const float*)d_in[0];
  const float* cw1 = (const float*)d_in[1];
  const float* cb1 = (const float*)d_in[2];
  const float* cw2 = (const float*)d_in[3];
  const float* cb2 = (const float*)d_in[4];
  const float* cw3 = (const float*)d_in[5];
  const float* cb3 = (const float*)d_in[6];
  const float* fw1 = (const float*)d_in[7];
  const float* fb1 = (const float*)d_in[8];
  const float* fw2 = (const float*)d_in[9];
  const float* fb2 = (const float*)d_in[10];
  const float* z   = (const float*)d_in[11];

  float* ws = (float*)d_ws;
  // c1: [0, 13107200)            1024*32*400
  // c2: [13107200, 18415616)     1024*64*81
  // c3: [0, 3211264)             reuses dead c1
  // pw: [13107200, 15204352)     8*1024*256, reuses dead c2
  // h : [15204352, 15466496)
  float* c1 = ws;
  float* c2 = ws + 13107200;
  float* c3 = ws;
  float* pw = ws + 13107200;
  float* h  = ws + 15204352;

  float* dist = (float*)d_out;
  float* res  = dist + 1024 * 6 * 51;

  conv1_k<<<1024, 320, 0, stream>>>(x, cw1, cb1, c1);
  conv2_k<<<1024, 320, 0, stream>>>(c1, cw2, cb2, c2);
  conv3_k<<<1024, 256, 0, stream>>>(c2, cw3, cb3, c3);
  fc1a_k<<<dim3(64, 8), 256, 0, stream>>>(c3, fw1, pw);
  fc1b_k<<<1024, 256, 0, stream>>>(pw, fb1, h);
  fc2_k<<<256, 256, 0, stream>>>(h, fw2, fb2, z, dist, res);
}

// Round 3
// 721.315 us; speedup vs baseline: 1.3164x; 1.2483x over previous
//
#include <hip/hip_runtime.h>

#define RL(x) __builtin_amdgcn_readfirstlane(x)

// ---------------- conv1: x[1024,4,84,84] -> c1[1024,32,20,20], k=8, s=4 ----------------
// Pixels on lanes (p = lane + 64s, 7 slots over 400 px), 4 waves = 4 oc-groups of 8.
// Weights staged once to LDS as [ic][ky][oc][kx] (8KB); per (ic,ky) the wave
// broadcasts its 8x8 weight block into VGPRs (ds_read_b128, conflict-free),
// then 7 slots x 64 FMAs of per-lane coalesced float4 input loads.
__global__ __launch_bounds__(256, 2) void conv1_k(const float* __restrict__ x,
                                                  const float* __restrict__ w,    // [32,4,8,8]
                                                  const float* __restrict__ bias,
                                                  float* __restrict__ out) {
  __shared__ float wl[8192];
  const int b    = blockIdx.x;
  const int tid  = threadIdx.x;
  const int lane = tid & 63;
  const int g    = RL(tid >> 6);   // oc-group: oc = g*8 + j

  // stage weights: src w[oc*256 + rem], rem = ic*64+ky*8+kx -> wl[(rem>>3)*256 + oc*8 + (rem&7)]
#pragma unroll
  for (int i = 0; i < 32; ++i) {
    int idx = tid + i * 256;
    int oc = idx >> 8, rem = idx & 255;
    wl[(rem >> 3) * 256 + oc * 8 + (rem & 7)] = w[idx];
  }
  __syncthreads();

  int pv[7], ib[7];
#pragma unroll
  for (int s = 0; s < 7; ++s) {
    int p = lane + 64 * s;
    pv[s] = (p < 400);
    if (p > 399) p = 399;
    int py = p / 20, px = p - py * 20;
    ib[s] = py * 336 + px * 4;   // (4py)*84 + 4px
  }

  float acc[7][8];
#pragma unroll
  for (int s = 0; s < 7; ++s)
#pragma unroll
    for (int j = 0; j < 8; ++j) acc[s][j] = 0.f;

  const float* xb = x + b * 28224;
#pragma unroll 1
  for (int ic = 0; ic < 4; ++ic) {
#pragma unroll 1
    for (int ky = 0; ky < 8; ++ky) {
      const float* wp = &wl[(ic * 8 + ky) * 256 + g * 64];
      float wr[8][8];
#pragma unroll
      for (int j = 0; j < 8; ++j) {
        float4 w0 = *(const float4*)(wp + j * 8);
        float4 w1 = *(const float4*)(wp + j * 8 + 4);
        wr[j][0]=w0.x; wr[j][1]=w0.y; wr[j][2]=w0.z; wr[j][3]=w0.w;
        wr[j][4]=w1.x; wr[j][5]=w1.y; wr[j][6]=w1.z; wr[j][7]=w1.w;
      }
      const float* rp = xb + ic * 7056 + ky * 84;
#pragma unroll
      for (int s = 0; s < 7; ++s) {
        float4 a = *(const float4*)(rp + ib[s]);
        float4 c = *(const float4*)(rp + ib[s] + 4);
        float in8[8] = {a.x, a.y, a.z, a.w, c.x, c.y, c.z, c.w};
#pragma unroll
        for (int j = 0; j < 8; ++j)
#pragma unroll
          for (int kx = 0; kx < 8; ++kx)
            acc[s][j] = fmaf(in8[kx], wr[j][kx], acc[s][j]);
      }
    }
  }

  const float inv256 = 1.0f / 256.0f;
#pragma unroll
  for (int j = 0; j < 8; ++j) {
    float bj = bias[g * 8 + j];
    float* op = out + (b * 32 + g * 8 + j) * 400;
#pragma unroll
    for (int s = 0; s < 7; ++s) {
      if (pv[s]) {
        float v = acc[s][j] * inv256 + bj;
        op[lane + 64 * s] = v > 0.f ? v : 0.f;
      }
    }
  }
}

// ---------------- conv2: c1[1024,32,20,20] -> c2[1024,64,9,9], k=4, s=2 ----------------
// lanes = 64 oc; wave w owns output rows {2w,2w+1} (wave 4: row 8). 6-row scheme:
// input row r (of 6) feeds acc[0] via ky=r (r<4) and acc[1] via ky=r-2 (r>=2),
// halving uniform row loads; ic pairs unrolled for two independent load chains.
__global__ __launch_bounds__(320, 2) void conv2_k(const float* __restrict__ in,
                                                  const float* __restrict__ w,   // [64,32,4,4]
                                                  const float* __restrict__ bias,
                                                  float* __restrict__ out) {
  const int b   = blockIdx.x;
  const int tid = threadIdx.x;
  const int j   = tid & 63;
  const int wv  = RL(tid >> 6);        // 0..4
  const int py0 = 2 * wv;
  const int nr  = (wv == 4) ? 1 : 2;
  const int rmax = (wv == 4) ? 4 : 6;

  float acc[2][9];
#pragma unroll
  for (int rr = 0; rr < 2; ++rr)
#pragma unroll
    for (int px = 0; px < 9; ++px) acc[rr][px] = 0.f;

  const float* inb = in + b * 12800 + wv * 80;   // input row 4wv
  const float* wj  = w + j * 512;

#pragma unroll 1
  for (int ic2 = 0; ic2 < 16; ++ic2) {
#pragma unroll
    for (int e = 0; e < 2; ++e) {
      const int ic = ic2 * 2 + e;
      float wk[16];
#pragma unroll
      for (int q = 0; q < 4; ++q) {
        float4 t = *(const float4*)(wj + ic * 16 + q * 4);
        wk[q*4]=t.x; wk[q*4+1]=t.y; wk[q*4+2]=t.z; wk[q*4+3]=t.w;
      }
      const float* icp = inb + ic * 400;
#pragma unroll
      for (int r = 0; r < 6; ++r) {
        if (r < rmax) {
          float rw[20];
#pragma unroll
          for (int q = 0; q < 5; ++q) {
            float4 t = *(const float4*)(icp + r * 20 + q * 4);
            rw[q*4]=t.x; rw[q*4+1]=t.y; rw[q*4+2]=t.z; rw[q*4+3]=t.w;
          }
          if (r < 4) {
#pragma unroll
            for (int px = 0; px < 9; ++px)
#pragma unroll
              for (int kx = 0; kx < 4; ++kx)
                acc[0][px] = fmaf(rw[2*px+kx], wk[r*4+kx], acc[0][px]);
          }
          if (r >= 2 && nr == 2) {
#pragma unroll
            for (int px = 0; px < 9; ++px)
#pragma unroll
              for (int kx = 0; kx < 4; ++kx)
                acc[1][px] = fmaf(rw[2*px+kx], wk[(r-2)*4+kx], acc[1][px]);
          }
        }
      }
    }
  }

  const float bj = bias[j];
#pragma unroll
  for (int rr = 0; rr < 2; ++rr) {
    if (rr < nr) {
      float* op = out + (b * 64 + j) * 81 + (py0 + rr) * 9;
#pragma unroll
      for (int px = 0; px < 9; ++px) {
        float v = acc[rr][px] + bj;
        op[px] = v > 0.f ? v : 0.f;
      }
    }
  }
}

// ---------------- conv3: c2[1024,64,9,9] -> c3[1024,64,7,7], k=3, s=1 ----------------
// lanes = 64 oc; wave (rotated by b) owns rows {2w,2w+1} (wave 3: row 6).
// Weights staged to LDS in 16-ic chunks, layout [icrel][oc][t] so lane reads are
// stride-9 (gcd(9,32)=1 -> 2 lanes/bank = free), killing the 64-line/instr
// global weight scatter of R1. Input rows via uniform loads (parity-static float2).
__global__ __launch_bounds__(256, 2) void conv3_k(const float* __restrict__ in,
                                                  const float* __restrict__ w,   // [64,64,3,3]
                                                  const float* __restrict__ bias,
                                                  float* __restrict__ out) {
  __shared__ float wl[9216];   // 16 ic * 64 oc * 9
  const int b   = blockIdx.x;
  const int tid = threadIdx.x;
  const int j   = tid & 63;
  const int wv  = (RL(tid >> 6) + b) & 3;
  const int py0 = 2 * wv;
  const int nr  = (wv == 3) ? 1 : 2;

  float acc[2][7];
#pragma unroll
  for (int rr = 0; rr < 2; ++rr)
#pragma unroll
    for (int px = 0; px < 7; ++px) acc[rr][px] = 0.f;

  const float* inb = in + b * 5184;

#pragma unroll 1
  for (int c4 = 0; c4 < 4; ++c4) {
    const int ic0 = c4 * 16;
    __syncthreads();
#pragma unroll 1
    for (int i = 0; i < 36; ++i) {
      int idx = tid + i * 256;              // 9216 = 36*256
      int oc  = idx / 144;
      int rem = idx - oc * 144;             // icrel*9 + t
      int icrel = rem / 9;
      int t     = rem - icrel * 9;
      wl[(icrel * 64 + oc) * 9 + t] = w[oc * 576 + ic0 * 9 + rem];
    }
    __syncthreads();

#pragma unroll 1
    for (int ii2 = 0; ii2 < 8; ++ii2) {
#pragma unroll
      for (int e = 0; e < 2; ++e) {
        const int icr = ii2 * 2 + e;
        const int ic  = ic0 + icr;
        const float* wp = &wl[(icr * 64 + j) * 9];
        float w9[9];
#pragma unroll
        for (int t = 0; t < 9; ++t) w9[t] = wp[t];
        const float* icp = inb + ic * 81;
#pragma unroll
        for (int ky = 0; ky < 3; ++ky) {
          const int r = py0 + ky;
          const float* bp = icp + r * 9;
          // parity of (ic*81 + r*9) = (e + ky) & 1 (ic0, py0 even) — static
          float in18[18];
          if (nr == 2) {
            if (((e + ky) & 1) == 0) {
#pragma unroll
              for (int q = 0; q < 9; ++q) {
                float2 t = *(const float2*)(bp + 2 * q);
                in18[2*q] = t.x; in18[2*q+1] = t.y;
              }
            } else {
              in18[0] = bp[0];
#pragma unroll
              for (int q = 0; q < 8; ++q) {
                float2 t = *(const float2*)(bp + 1 + 2 * q);
                in18[1+2*q] = t.x; in18[2+2*q] = t.y;
              }
              in18[17] = bp[17];
            }
          } else {
            if (((e + ky) & 1) == 0) {
#pragma unroll
              for (int q = 0; q < 4; ++q) {
                float2 t = *(const float2*)(bp + 2 * q);
                in18[2*q] = t.x; in18[2*q+1] = t.y;
              }
              in18[8] = bp[8];
            } else {
              in18[0] = bp[0];
#pragma unroll
              for (int q = 0; q < 4; ++q) {
                float2 t = *(const float2*)(bp + 1 + 2 * q);
                in18[1+2*q] = t.x; in18[2+2*q] = t.y;
              }
            }
#pragma unroll
            for (int q = 9; q < 18; ++q) in18[q] = 0.f;
          }
#pragma unroll
          for (int rr = 0; rr < 2; ++rr) {
            if (rr < nr) {
#pragma unroll
              for (int px = 0; px < 7; ++px)
#pragma unroll
                for (int kx = 0; kx < 3; ++kx)
                  acc[rr][px] = fmaf(in18[rr*9 + px + kx], w9[ky*3 + kx], acc[rr][px]);
            }
          }
        }
      }
    }
  }

  const float bj = bias[j];
#pragma unroll
  for (int rr = 0; rr < 2; ++rr) {
    if (rr < nr) {
      float* op = out + b * 3136 + j * 49 + (py0 + rr) * 7;
#pragma unroll
      for (int px = 0; px < 7; ++px) {
        float v = acc[rr][px] + bj;
        op[px] = v > 0.f ? v : 0.f;
      }
    }
  }
}

// ---------------- fc1a: c3[1024][3136] @ fw1[3136][256] -> partial[8][1024][256] ----------------
__global__ __launch_bounds__(256) void fc1a_k(const float* __restrict__ a,
                                              const float* __restrict__ w,
                                              float* __restrict__ part) {
  __shared__ float al[56][20];
  const int b0  = blockIdx.x * 16;
  const int k0  = blockIdx.y * 392;
  const int tid = threadIdx.x;
  const int jj  = tid & 63;
  const int ib  = RL(tid >> 6);

  float acc[4][4];
#pragma unroll
  for (int r = 0; r < 4; ++r)
#pragma unroll
    for (int c = 0; c < 4; ++c) acc[r][c] = 0.f;

#pragma unroll 1
  for (int t = 0; t < 7; ++t) {
    __syncthreads();
#pragma unroll
    for (int z = 0; z < 4; ++z) {
      int idx = tid + z * 256;
      if (idx < 896) {
        int i = idx / 56, kk = idx - i * 56;
        al[kk][i] = a[(b0 + i) * 3136 + k0 + t * 56 + kk];
      }
    }
    __syncthreads();
#pragma unroll 2
    for (int kk = 0; kk < 56; ++kk) {
      float4 wv4 = *(const float4*)&w[(k0 + t * 56 + kk) * 256 + jj * 4];
      float4 av  = *(const float4*)&al[kk][ib * 4];
      float avr[4] = {av.x, av.y, av.z, av.w};
#pragma unroll
      for (int r = 0; r < 4; ++r) {
        acc[r][0] = fmaf(avr[r], wv4.x, acc[r][0]);
        acc[r][1] = fmaf(avr[r], wv4.y, acc[r][1]);
        acc[r][2] = fmaf(avr[r], wv4.z, acc[r][2]);
        acc[r][3] = fmaf(avr[r], wv4.w, acc[r][3]);
      }
    }
  }
#pragma unroll
  for (int r = 0; r < 4; ++r) {
    float4 v = {acc[r][0], acc[r][1], acc[r][2], acc[r][3]};
    *(float4*)&part[(blockIdx.y * 1024 + b0 + ib * 4 + r) * 256 + jj * 4] = v;
  }
}

// ---------------- fc1b: reduce 8 partials + bias + relu -> h[1024][256] ----------------
__global__ __launch_bounds__(256) void fc1b_k(const float* __restrict__ part,
                                              const float* __restrict__ bias,
                                              float* __restrict__ h) {
  int idx = blockIdx.x * 256 + threadIdx.x;
  int j = idx & 255;
  float s = bias[j];
#pragma unroll
  for (int c = 0; c < 8; ++c) s += part[c * 262144 + idx];
  h[idx] = s > 0.f ? s : 0.f;
}

// ---------------- fc2 + softmax + dist/res ----------------
__global__ __launch_bounds__(256) void fc2_k(const float* __restrict__ h,
                                             const float* __restrict__ w,   // [256][51]
                                             const float* __restrict__ bias,
                                             const float* __restrict__ z,
                                             float* __restrict__ dist,      // [1024][6][51]
                                             float* __restrict__ res) {     // [1024][6]
  const int tid = threadIdx.x;
  const int j   = tid & 63;
  const int b   = blockIdx.x * 4 + RL(tid >> 6);
  const float* hb = h + b * 256;
  const int jc = j < 51 ? j : 50;
  float acc = bias[jc];
#pragma unroll 4
  for (int k = 0; k < 256; ++k)
    acc = fmaf(hb[k], w[k * 51 + jc], acc);
  float logit = (j < 51) ? acc : -1e30f;
  float m = logit;
#pragma unroll
  for (int o = 32; o > 0; o >>= 1) m = fmaxf(m, __shfl_xor(m, o, 64));
  float e = (j < 51) ? __expf(logit - m) : 0.f;
  float ssum = e;
#pragma unroll
  for (int o = 32; o > 0; o >>= 1) ssum += __shfl_xor(ssum, o, 64);
  float p = e / ssum;
  float zv = (j < 51) ? z[jc] : 0.f;
  float rz = p * zv;
#pragma unroll
  for (int o = 32; o > 0; o >>= 1) rz += __shfl_xor(rz, o, 64);
  if (j < 51) {
    float* db = dist + b * 6 * 51 + j;
#pragma unroll
    for (int n = 0; n < 6; ++n) db[n * 51] = p;
  }
  if (j < 6) res[b * 6 + j] = rz;
}

extern "C" void kernel_launch(void* const* d_in, const int* in_sizes, int n_in,
                              void* d_out, int out_size, void* d_ws, size_t ws_size,
                              hipStream_t stream) {
  const float* x   = (const float*)d_in[0];
  const float* cw1 = (const float*)d_in[1];
  const float* cb1 = (const float*)d_in[2];
  const float* cw2 = (const float*)d_in[3];
  const float* cb2 = (const float*)d_in[4];
  const float* cw3 = (const float*)d_in[5];
  const float* cb3 = (const float*)d_in[6];
  const float* fw1 = (const float*)d_in[7];
  const float* fb1 = (const float*)d_in[8];
  const float* fw2 = (const float*)d_in[9];
  const float* fb2 = (const float*)d_in[10];
  const float* z   = (const float*)d_in[11];

  float* ws = (float*)d_ws;
  float* c1 = ws;                  // 1024*32*400
  float* c2 = ws + 13107200;       // 1024*64*81
  float* c3 = ws;                  // reuses dead c1
  float* pw = ws + 13107200;       // 8*1024*256, reuses dead c2
  float* h  = ws + 15204352;       // 1024*256

  float* dist = (float*)d_out;
  float* res  = dist + 1024 * 6 * 51;

  conv1_k<<<1024, 256, 0, stream>>>(x, cw1, cb1, c1);
  conv2_k<<<1024, 320, 0, stream>>>(c1, cw2, cb2, c2);
  conv3_k<<<1024, 256, 0, stream>>>(c2, cw3, cb3, c3);
  fc1a_k<<<dim3(64, 8), 256, 0, stream>>>(c3, fw1, pw);
  fc1b_k<<<1024, 256, 0, stream>>>(pw, fb1, h);
  fc2_k<<<256, 256, 0, stream>>>(h, fw2, fb2, z, dist, res);
}